// Round 14
// baseline (386.778 us; speedup 1.0000x reference)
//
#include <hip/hip_runtime.h>

#define NN 512
#define DD 9
#define LL 32
#define NT 32   // 16x16 tiles per dimension
#define TL 48   // stored lanes per tile (kg3 zero-group elided)
#define PG 17   // part row stride (u32): odd -> conflict-free epilogue reads

typedef _Float16 f16x8 __attribute__((ext_vector_type(8)));
typedef float    f32x4 __attribute__((ext_vector_type(4)));

// Scan: pass-local wave wp owns 4 row-tiles {4wp..4wp+3} of the "a side",
// scans all 32 "b side" tiles. Pipelined one jj deep (MFMAs for jj issue
// before jj-1's pack/min VALU). Tiles store 48 lanes; lanes 48-63 substitute
// zero fragments in registers (their k-slots are zero padding; their C-rows
// are still valid MFMA outputs). Tracking: pk = (dbits & ~31)|jj, fminf =
// 2 VALU/cell; (d_trunc, jj) min == first-index argmin per lane col set
// col = (lane&15) + 16*jj (proven exact: R11/R13 absmax 0.0).
__device__ __forceinline__ void min_scan4(const f16x8* __restrict__ sAs,
                                          const f16x8* __restrict__ sBs,
                                          unsigned (* __restrict__ part)[PG],
                                          int wp, int lane)
{
    const int  ti0 = wp * 4;
    const bool act = lane < TL;

    f16x8 afr[4] = {};
    if (act) {
        #pragma unroll
        for (int q = 0; q < 4; ++q) afr[q] = sAs[(ti0 + q) * TL + lane];
    }

    float bm[16];
    #pragma unroll
    for (int i = 0; i < 16; ++i) bm[i] = 1e30f;

    const f32x4 zero = {0.f, 0.f, 0.f, 0.f};

    f16x8 cur = {};
    if (act) cur = sBs[lane];
    f32x4 dp[4];
    #pragma unroll
    for (int q = 0; q < 4; ++q)
        dp[q] = __builtin_amdgcn_mfma_f32_16x16x32_f16(afr[q], cur, zero, 0, 0, 0);

    #pragma unroll
    for (int jj = 1; jj < NT; ++jj) {
        f16x8 nxt = {};
        if (act) nxt = sBs[jj * TL + lane];
        f32x4 dn[4];
        #pragma unroll
        for (int q = 0; q < 4; ++q)
            dn[q] = __builtin_amdgcn_mfma_f32_16x16x32_f16(afr[q], nxt, zero, 0, 0, 0);
        #pragma unroll
        for (int q = 0; q < 4; ++q) {
            #pragma unroll
            for (int r = 0; r < 4; ++r) {
                unsigned pk = (__float_as_uint(dp[q][r]) & 0xFFFFFFE0u) | (unsigned)(jj - 1);
                bm[q * 4 + r] = fminf(bm[q * 4 + r], __uint_as_float(pk));
            }
        }
        #pragma unroll
        for (int q = 0; q < 4; ++q) dp[q] = dn[q];
    }
    #pragma unroll
    for (int q = 0; q < 4; ++q) {
        #pragma unroll
        for (int r = 0; r < 4; ++r) {
            unsigned pk = (__float_as_uint(dp[q][r]) & 0xFFFFFFE0u) | (unsigned)(NT - 1);
            bm[q * 4 + r] = fminf(bm[q * 4 + r], __uint_as_float(pk));
        }
    }

    const int g  = lane & 15;
    const int rb = (lane >> 4) << 2;
    #pragma unroll
    for (int q = 0; q < 4; ++q) {
        #pragma unroll
        for (int r = 0; r < 4; ++r) {
            const int row = (ti0 + q) * 16 + rb + r;
            part[row][g] = __float_as_uint(bm[q * 4 + r]);
        }
    }
}

// One block per batch, 1024 threads = 16 waves. Waves 0-7: pass 1 (input rows
// vs pred cols); waves 8-15: pass 2 operand-swapped. Class arrays staged in
// LDS so the argmin-indexed 9-float gathers are LDS reads, not global scatter.
// Histogram via wave ballots (no atomics). LDS total ~155.6 KB.
__global__ __launch_bounds__(1024, 4)
void loss_kernel(const float* __restrict__ kine_input,
                 const float* __restrict__ class_input,
                 const float* __restrict__ kine_pred,
                 const float* __restrict__ class_pred,
                 const float* __restrict__ mu,
                 const float* __restrict__ log_var,
                 float* __restrict__ out)
{
    const int b    = (int)blockIdx.x;
    const int t    = (int)threadIdx.x;
    const int lane = t & 63;
    const int wave = t >> 6;

    __shared__ f16x8    sA[NT * TL];        // input-side fragments, 24 KB
    __shared__ f16x8    sB[NT * TL];        // pred-side fragments,  24 KB
    __shared__ unsigned part[2][NN][PG];    // packed per-(row,g) minima, 69.6 KB
    __shared__ float4   s_ci4[NN * DD / 4]; // class_input staged, 18.4 KB
    __shared__ float4   s_cp4[NN * DD / 4]; // class_pred  staged, 18.4 KB
    __shared__ float    hist_w[16][DD];     // per-wave ballot counts
    __shared__ float    red[16];
    __shared__ float    s_kl;

    // ---- stage class arrays (vectorized, coalesced): 2x 1152 float4 ----
    {
        const float4* ci4 = reinterpret_cast<const float4*>(class_input + (size_t)b * NN * DD);
        const float4* cp4 = reinterpret_cast<const float4*>(class_pred  + (size_t)b * NN * DD);
        #pragma unroll
        for (int i = t; i < NN * DD / 4; i += 1024) {
            s_ci4[i] = ci4[i];
            s_cp4[i] = cp4[i];
        }
    }

    // ---- stage fragments: slot s = rep*1024+t -> side|ti|ln (3x1024 = 3072) ----
    // ln in 0..47: row/col = ti*16 + (ln&15), kg = ln>>4 (0..2), k = kg*8+e.
    // k0..15 cross: A kg0=hi(-2x) kg1=lo(-2x); B e<4=hi(y) else lo(y).
    // kg==2, e<4 norms: (A,B) = (1,y2hi),(1,y2lo),(x2hi,1),(x2lo,1); e>=4 zero.
    #pragma unroll
    for (int rep = 0; rep < 3; ++rep) {
        const int s    = rep * 1024 + t;
        const int side = s / (NT * TL);
        const int w2   = s - side * (NT * TL);
        const int ti   = w2 / TL;
        const int ln   = w2 - ti * TL;
        const int row  = ti * 16 + (ln & 15);
        const int kg   = ln >> 4;
        const float* P = side ? kine_pred : kine_input;
        float4 pt = *reinterpret_cast<const float4*>(P + ((size_t)b * NN + row) * 4);
        float n = pt.x*pt.x + pt.y*pt.y + pt.z*pt.z + pt.w*pt.w;
        float w[4];
        if (side == 0) { w[0] = -2.f*pt.x; w[1] = -2.f*pt.y; w[2] = -2.f*pt.z; w[3] = -2.f*pt.w; }
        else           { w[0] =      pt.x; w[1] =      pt.y; w[2] =      pt.z; w[3] =      pt.w; }
        _Float16 hi[4], lo[4];
        #pragma unroll
        for (int c = 0; c < 4; ++c) { hi[c] = (_Float16)w[c]; lo[c] = (_Float16)(w[c] - (float)hi[c]); }
        const _Float16 nhi = (_Float16)n;
        const _Float16 nlo = (_Float16)(n - (float)nhi);
        const _Float16 one = (_Float16)1.f;
        f16x8 hv;
        #pragma unroll
        for (int e = 0; e < 8; ++e) {
            _Float16 v = (_Float16)0.f;
            if (kg < 2) {
                const int c = e & 3;
                if (side == 0) v = (kg == 0) ? hi[c] : lo[c];
                else           v = (e < 4) ? hi[c] : lo[c];
            } else if (e < 4) {   // kg == 2
                if (side == 0) v = (e == 0 || e == 1) ? one : ((e == 2) ? nhi : nlo);
                else           v = (e == 0) ? nhi : ((e == 1) ? nlo : one);
            }
            hv[e] = v;
        }
        (side ? sB : sA)[ti * TL + ln] = hv;
    }
    __syncthreads();

    // ---- concurrent transposed scans on wave halves ----
    if (wave < 8) min_scan4(sA, sB, part[0], wave,     lane);
    else          min_scan4(sB, sA, part[1], wave - 8, lane);

    const int ep_p  = t >> 9;                // pass (uniform per wave)
    const int ep_lr = t & (NN - 1);          // row within pass
    const float* s_ci = reinterpret_cast<const float*>(s_ci4);
    const float* s_cp = reinterpret_cast<const float*>(s_cp4);
    const float* s_own = ep_p ? s_cp : s_ci;
    const float* s_oth = ep_p ? s_ci : s_cp;

    // ---- histogram via wave ballots (no atomics) ----
    {
        float mx = s_own[ep_lr * DD]; int lab = 0;
        #pragma unroll
        for (int d2 = 1; d2 < DD; ++d2) {
            float v = s_own[ep_lr * DD + d2];
            if (v > mx) { mx = v; lab = d2; }       // argmax(exp)==argmax; first-index ties
        }
        #pragma unroll
        for (int c = 0; c < DD; ++c) {
            unsigned long long m = __ballot(lab == c);
            if (lane == 0) hist_w[wave][c] = (float)__popcll(m);
        }
    }
    // ---- KL (wave 0) ----
    if (t < 64) {
        float v = 0.f;
        if (t < LL) {
            float m_ = mu[(size_t)b * LL + t];
            float lv = log_var[(size_t)b * LL + t];
            v = 1.f + lv - m_ * m_ - expf(lv);
        }
        #pragma unroll
        for (int off = 32; off > 0; off >>= 1) v += __shfl_down(v, off, 64);
        if (t == 0) s_kl = -0.5f * v;
    }
    __syncthreads();

    // ---- merge 16 groups + epilogue (all operands now in LDS) ----
    // Ascending g with strict float <: (d_trunc, jj, g) lex == (d_trunc, col).
    float partsum;
    {
        const unsigned* pr = part[ep_p][ep_lr];
        unsigned e = pr[0]; int bg = 0;
        #pragma unroll
        for (int g = 1; g < 16; ++g) {
            unsigned v = pr[g];
            if (__uint_as_float(v) < __uint_as_float(e)) { e = v; bg = g; }
        }
        const int   idx  = bg + 16 * (int)(e & 31u);
        const float dmin = fmaxf(__uint_as_float(e & 0xFFFFFFE0u), 0.f);  // clamp commutes with min
        float dot = 0.f;
        #pragma unroll
        for (int d2 = 0; d2 < DD; ++d2)
            dot += s_own[ep_lr * DD + d2] * s_oth[idx * DD + d2];
        partsum = dmin - dot;   // chamfer + (-1)*class dot (W=1)
    }
    #pragma unroll
    for (int off = 32; off > 0; off >>= 1) partsum += __shfl_down(partsum, off, 64);
    if (lane == 0) red[wave] = partsum;
    __syncthreads();

    if (t == 0) {
        float sum = 0.f;
        #pragma unroll
        for (int w2 = 0; w2 < 16; ++w2) sum += red[w2];
        float cnum = 0.f;
        #pragma unroll
        for (int c = 0; c < DD; ++c) {
            float cin = 0.f, cpr = 0.f;
            #pragma unroll
            for (int w2 = 0; w2 < 8; ++w2) { cin += hist_w[w2][c]; cpr += hist_w[8 + w2][c]; }
            float diff = fabsf(cpr - cin);
            float wgt = (c == 0) ? 2.0f : ((c == DD - 1) ? 100.0f : 1.0f);
            cnum += wgt * diff;
        }
        out[b] = 0.99f * (sum + 0.001f * cnum) + 0.01f * s_kl;
    }
}

extern "C" void kernel_launch(void* const* d_in, const int* in_sizes, int n_in,
                              void* d_out, int out_size, void* d_ws, size_t ws_size,
                              hipStream_t stream) {
    const float* kine_input  = (const float*)d_in[0];
    const float* class_input = (const float*)d_in[1];
    const float* kine_pred   = (const float*)d_in[2];
    const float* class_pred  = (const float*)d_in[3];
    const float* mu          = (const float*)d_in[4];
    const float* log_var     = (const float*)d_in[5];
    float* out = (float*)d_out;

    loss_kernel<<<256, 1024, 0, stream>>>(kine_input, class_input, kine_pred,
                                          class_pred, mu, log_var, out);
}

// Round 15
// 332.576 us; speedup vs baseline: 1.1630x; 1.1630x over previous
//
#include <hip/hip_runtime.h>

#define NN 512
#define DD 9
#define LL 32
#define NT 32   // 16x16 tiles per dimension
#define PG 9    // merged col-groups per row (8 used + pad slot not needed; 9 = stride)

typedef _Float16 f16x8 __attribute__((ext_vector_type(8)));
typedef float    f32x4 __attribute__((ext_vector_type(4)));

// Scan (R13-proven form: TL=64, unconditional loads, 1-jj software pipeline).
// Wave wp owns 4 row-tiles {4wp..4wp+3} of the "a side", scans all 32 "b side"
// tiles. MFMA emits complete distance (cross hi/lo split k0..15, norms
// k16..19). Tracking: pk = (dbits & ~31)|jj, fminf = 2 VALU/cell; (d_trunc,
// jj) min == first-index argmin per lane col set col = (lane&15) + 16*jj.
// Tail: one xor-8 butterfly lex-merges groups g/g+8 on explicit (d, col);
// lanes with (lane&8)==0 write part_d/part_c[row][g], g in 0..7.
__device__ __forceinline__ void min_scan4(const f16x8* __restrict__ sAs,
                                          const f16x8* __restrict__ sBs,
                                          float    (* __restrict__ part_d)[PG],
                                          unsigned short (* __restrict__ part_c)[PG],
                                          int wp, int lane)
{
    const int ti0 = wp * 4;
    f16x8 afr[4];
    #pragma unroll
    for (int q = 0; q < 4; ++q) afr[q] = sAs[(ti0 + q) * 64 + lane];

    float bm[16];
    #pragma unroll
    for (int i = 0; i < 16; ++i) bm[i] = 1e30f;

    const f32x4 zero = {0.f, 0.f, 0.f, 0.f};

    f16x8 cur = sBs[lane];
    f32x4 dp[4];
    #pragma unroll
    for (int q = 0; q < 4; ++q)
        dp[q] = __builtin_amdgcn_mfma_f32_16x16x32_f16(afr[q], cur, zero, 0, 0, 0);

    #pragma unroll
    for (int jj = 1; jj < NT; ++jj) {
        cur = sBs[jj * 64 + lane];
        f32x4 dn[4];
        #pragma unroll
        for (int q = 0; q < 4; ++q)
            dn[q] = __builtin_amdgcn_mfma_f32_16x16x32_f16(afr[q], cur, zero, 0, 0, 0);
        // pack/min jj-1's results while jj's MFMAs are in flight
        #pragma unroll
        for (int q = 0; q < 4; ++q) {
            #pragma unroll
            for (int r = 0; r < 4; ++r) {
                unsigned pk = (__float_as_uint(dp[q][r]) & 0xFFFFFFE0u) | (unsigned)(jj - 1);
                bm[q * 4 + r] = fminf(bm[q * 4 + r], __uint_as_float(pk));
            }
        }
        #pragma unroll
        for (int q = 0; q < 4; ++q) dp[q] = dn[q];
    }
    #pragma unroll
    for (int q = 0; q < 4; ++q) {
        #pragma unroll
        for (int r = 0; r < 4; ++r) {
            unsigned pk = (__float_as_uint(dp[q][r]) & 0xFFFFFFE0u) | (unsigned)(NT - 1);
            bm[q * 4 + r] = fminf(bm[q * 4 + r], __uint_as_float(pk));
        }
    }

    // xor-8 butterfly: lex-merge col-groups g and g+8 on explicit (d, col)
    const int g  = lane & 15;
    const int rb = (lane >> 4) << 2;
    #pragma unroll
    for (int i = 0; i < 16; ++i) {
        unsigned pk  = __float_as_uint(bm[i]);
        float    d   = __uint_as_float(pk & 0xFFFFFFE0u);
        unsigned col = (unsigned)g + 16u * (pk & 31u);
        float    qd  = __shfl_xor(d, 8, 64);
        unsigned qc  = (unsigned)__shfl_xor((int)col, 8, 64);
        bool take = (qd < d) || (qd == d && qc < col);
        d   = take ? qd : d;
        col = take ? qc : col;
        if ((lane & 8) == 0) {
            const int row = (ti0 + (i >> 2)) * 16 + rb + (i & 3);
            part_d[row][g] = d;                       // g in 0..7 here
            part_c[row][g] = (unsigned short)col;
        }
    }
}

// One block per batch, 1024 threads = 16 waves. Waves 0-7: pass 1 (input rows
// vs pred cols); waves 8-15: pass 2 operand-swapped. Class arrays staged in
// LDS (epilogue gathers become LDS reads); histogram via wave ballots.
__global__ __launch_bounds__(1024, 4)
void loss_kernel(const float* __restrict__ kine_input,
                 const float* __restrict__ class_input,
                 const float* __restrict__ kine_pred,
                 const float* __restrict__ class_pred,
                 const float* __restrict__ mu,
                 const float* __restrict__ log_var,
                 float* __restrict__ out)
{
    const int b    = (int)blockIdx.x;
    const int t    = (int)threadIdx.x;
    const int lane = t & 63;
    const int wave = t >> 6;

    __shared__ f16x8          sA[NT * 64];          // input-side fragments, 32 KB
    __shared__ f16x8          sB[NT * 64];          // pred-side fragments,  32 KB
    __shared__ float          part_d[2][NN][PG];    // merged min dists, 36.9 KB
    __shared__ unsigned short part_c[2][NN][PG];    // merged argmin cols, 18.4 KB
    __shared__ float4         s_ci4[NN * DD / 4];   // class_input staged, 18.4 KB
    __shared__ float4         s_cp4[NN * DD / 4];   // class_pred  staged, 18.4 KB
    __shared__ float          hist_w[16][DD];       // per-wave ballot counts
    __shared__ float          red[16];
    __shared__ float          s_kl;

    // ---- stage class arrays (coalesced float4; issue first to hide latency) ----
    {
        const float4* ci4 = reinterpret_cast<const float4*>(class_input + (size_t)b * NN * DD);
        const float4* cp4 = reinterpret_cast<const float4*>(class_pred  + (size_t)b * NN * DD);
        #pragma unroll
        for (int i = t; i < NN * DD / 4; i += 1024) {
            s_ci4[i] = ci4[i];
            s_cp4[i] = cp4[i];
        }
    }

    // ---- stage fragments: slot s = rep*1024+t -> side|ti|lane (R13 layout) ----
    // lane ln: row/col = ti*16 + (ln&15), kg = ln>>4, k = kg*8+e.
    // k0..15 cross: A kg0=hi(-2x) kg1=lo(-2x); B e<4=hi(y) else lo(y).
    // kg==2, e<4 norms: (A,B) = (1,y2hi),(1,y2lo),(x2hi,1),(x2lo,1). kg==3 zero.
    #pragma unroll
    for (int rep = 0; rep < 4; ++rep) {
        const int s    = rep * 1024 + t;
        const int side = s >> 11;
        const int ti   = (s >> 6) & 31;
        const int ln   = s & 63;
        const int row  = ti * 16 + (ln & 15);
        const int kg   = ln >> 4;
        const float* P = side ? kine_pred : kine_input;
        float4 pt = *reinterpret_cast<const float4*>(P + ((size_t)b * NN + row) * 4);
        float n = pt.x*pt.x + pt.y*pt.y + pt.z*pt.z + pt.w*pt.w;
        float w[4];
        if (side == 0) { w[0] = -2.f*pt.x; w[1] = -2.f*pt.y; w[2] = -2.f*pt.z; w[3] = -2.f*pt.w; }
        else           { w[0] =      pt.x; w[1] =      pt.y; w[2] =      pt.z; w[3] =      pt.w; }
        _Float16 hi[4], lo[4];
        #pragma unroll
        for (int c = 0; c < 4; ++c) { hi[c] = (_Float16)w[c]; lo[c] = (_Float16)(w[c] - (float)hi[c]); }
        const _Float16 nhi = (_Float16)n;
        const _Float16 nlo = (_Float16)(n - (float)nhi);
        const _Float16 one = (_Float16)1.f;
        f16x8 hv;
        #pragma unroll
        for (int e = 0; e < 8; ++e) {
            _Float16 v = (_Float16)0.f;
            if (kg < 2) {
                const int c = e & 3;
                if (side == 0) v = (kg == 0) ? hi[c] : lo[c];
                else           v = (e < 4) ? hi[c] : lo[c];
            } else if (kg == 2 && e < 4) {
                if (side == 0) v = (e == 0 || e == 1) ? one : ((e == 2) ? nhi : nlo);
                else           v = (e == 0) ? nhi : ((e == 1) ? nlo : one);
            }
            hv[e] = v;
        }
        (side ? sB : sA)[ti * 64 + ln] = hv;
    }
    __syncthreads();

    // ---- concurrent transposed scans on wave halves ----
    if (wave < 8) min_scan4(sA, sB, part_d[0], part_c[0], wave,     lane);
    else          min_scan4(sB, sA, part_d[1], part_c[1], wave - 8, lane);

    const int ep_p  = t >> 9;                // pass (wave-uniform)
    const int ep_lr = t & (NN - 1);          // row within pass
    const float* s_ci = reinterpret_cast<const float*>(s_ci4);
    const float* s_cp = reinterpret_cast<const float*>(s_cp4);
    const float* s_own = ep_p ? s_cp : s_ci;
    const float* s_oth = ep_p ? s_ci : s_cp;

    // ---- histogram via wave ballots (no atomics; class rows from LDS) ----
    {
        float mx = s_own[ep_lr * DD]; int lab = 0;
        #pragma unroll
        for (int d2 = 1; d2 < DD; ++d2) {
            float v = s_own[ep_lr * DD + d2];
            if (v > mx) { mx = v; lab = d2; }       // argmax(exp)==argmax; first-index ties
        }
        #pragma unroll
        for (int c = 0; c < DD; ++c) {
            unsigned long long m = __ballot(lab == c);
            if (lane == 0) hist_w[wave][c] = (float)__popcll(m);
        }
    }
    // ---- KL (wave 0) ----
    if (t < 64) {
        float v = 0.f;
        if (t < LL) {
            float m_ = mu[(size_t)b * LL + t];
            float lv = log_var[(size_t)b * LL + t];
            v = 1.f + lv - m_ * m_ - expf(lv);
        }
        #pragma unroll
        for (int off = 32; off > 0; off >>= 1) v += __shfl_down(v, off, 64);
        if (t == 0) s_kl = -0.5f * v;
    }
    __syncthreads();

    // ---- merge 8 groups + epilogue: thread t -> (pass ep_p, row ep_lr) ----
    // Explicit (d, col) lex merge: exact first-index semantics.
    float partsum;
    {
        float    bd = part_d[ep_p][ep_lr][0];
        unsigned bc = part_c[ep_p][ep_lr][0];
        #pragma unroll
        for (int g2 = 1; g2 < 8; ++g2) {
            float    d = part_d[ep_p][ep_lr][g2];
            unsigned c = part_c[ep_p][ep_lr][g2];
            if (d < bd || (d == bd && c < bc)) { bd = d; bc = c; }
        }
        const float dmin = fmaxf(bd, 0.f);   // clamp commutes with min (ref semantics)
        const int   idx  = (int)bc;
        float dot = 0.f;
        #pragma unroll
        for (int d2 = 0; d2 < DD; ++d2)
            dot += s_own[ep_lr * DD + d2] * s_oth[idx * DD + d2];
        partsum = dmin - dot;   // chamfer + (-1)*class dot (W=1)
    }
    #pragma unroll
    for (int off = 32; off > 0; off >>= 1) partsum += __shfl_down(partsum, off, 64);
    if (lane == 0) red[wave] = partsum;
    __syncthreads();

    if (t == 0) {
        float sum = 0.f;
        #pragma unroll
        for (int w2 = 0; w2 < 16; ++w2) sum += red[w2];
        float cnum = 0.f;
        #pragma unroll
        for (int c = 0; c < DD; ++c) {
            float cin = 0.f, cpr = 0.f;
            #pragma unroll
            for (int w2 = 0; w2 < 8; ++w2) { cin += hist_w[w2][c]; cpr += hist_w[8 + w2][c]; }
            float diff = fabsf(cpr - cin);
            float wgt = (c == 0) ? 2.0f : ((c == DD - 1) ? 100.0f : 1.0f);
            cnum += wgt * diff;
        }
        out[b] = 0.99f * (sum + 0.001f * cnum) + 0.01f * s_kl;
    }
}

extern "C" void kernel_launch(void* const* d_in, const int* in_sizes, int n_in,
                              void* d_out, int out_size, void* d_ws, size_t ws_size,
                              hipStream_t stream) {
    const float* kine_input  = (const float*)d_in[0];
    const float* class_input = (const float*)d_in[1];
    const float* kine_pred   = (const float*)d_in[2];
    const float* class_pred  = (const float*)d_in[3];
    const float* mu          = (const float*)d_in[4];
    const float* log_var     = (const float*)d_in[5];
    float* out = (float*)d_out;

    loss_kernel<<<256, 1024, 0, stream>>>(kine_input, class_input, kine_pred,
                                          class_pred, mu, log_var, out);
}